// Round 8
// baseline (127.539 us; speedup 1.0000x reference)
//
#include <hip/hip_runtime.h>

typedef float v2f __attribute__((ext_vector_type(2)));

#define NB 32
#define N0 20000
#define N1 10000
#define N2 10000
#define NPTS 40000
#define NTILES 313         // ceil(40000 / 128); 2 points per lane per iter
#define KC 8               // centers per block
#define TCHUNKS 4          // tile chunks per (b, side, cc)
#define SENT 3.0e4f        // sentinel coord: contribution ~ -1e-10, negligible

// 2048 blocks x 256 thr = 8 blocks/CU x 4 waves = 32 waves/CU cap.
// bid = ((b*2 + side)*8 + cc)*4 + tchunk. Pure VALU (no LDS table):
// per 2 pairs: 6 v_pk_* + 6 scalar VALU + 2 v_rcp (trans, overlapped).
__global__ __launch_bounds__(256, 8) void hat_kernel(
    const float* __restrict__ up0, const float* __restrict__ down0,
    const float* __restrict__ ext0, const float* __restrict__ ext1,
    const float* __restrict__ centers, const float* __restrict__ radius,
    float* __restrict__ out)
{
    const int tid    = threadIdx.x;
    const int lane   = tid & 63;
    const int wave   = tid >> 6;
    const int bid    = blockIdx.x;
    const int tchunk = bid & 3;
    const int cc     = (bid >> 2) & 7;
    const int side   = (bid >> 5) & 1;
    const int b      = bid >> 6;
    const int cbase  = cc * KC;

    const float r = fabsf(radius[0]);

    // rotated centers, negated, splatted into uniform v2f (SGPR pairs)
    v2f nuc[KC], nvc[KC];
    #pragma unroll
    for (int k = 0; k < KC; ++k) {
        const float cx = centers[2*(cbase+k)];
        const float cy = centers[2*(cbase+k)+1];
        nuc[k] = (v2f){-(cx + cy), -(cx + cy)};
        nvc[k] = (v2f){-(cx - cy), -(cx - cy)};
    }

    // float4 = 2 consecutive float2 points
    const float4* base0 = (const float4*)((side == 0 ? up0 : down0) + (size_t)b * (N0*2));
    const float4* e0f   = (const float4*)(ext0 + (size_t)b * (N1*2));
    const float4* e1f   = (const float4*)(ext1 + (size_t)b * (N2*2));

    v2f acc[KC];
    #pragma unroll
    for (int k = 0; k < KC; ++k) acc[k] = (v2f){0.f, 0.f};

    const v2f one2 = (v2f){1.f, 1.f};

    for (int t = tchunk*4 + wave; t < NTILES; t += TCHUNKS*4) {
        const int i = t*64 + lane;      // float4 index = two points
        v2f u_, v_;
        if (i < N0/2) {
            const float4 q = base0[i];
            u_ = (v2f){q.x + q.y, q.z + q.w};
            v_ = (v2f){q.x - q.y, q.z - q.w};
        } else if (i < (N0 + N1)/2) {
            const float4 q = e0f[i - N0/2];
            const float vv0 = (side == 0) ? q.y : q.x;   // up uses y, down x
            const float vv1 = (side == 0) ? q.w : q.z;
            // point = (vv, 1-vv): u = 1, v = 2vv-1
            u_ = one2;
            v_ = (v2f){2.f*vv0 - 1.f, 2.f*vv1 - 1.f};
        } else if (i < NPTS/2) {
            const float4 q = e1f[i - (N0 + N1)/2];
            const float vv0 = (side == 0) ? q.y : q.x;
            const float vv1 = (side == 0) ? q.w : q.z;
            u_ = one2;
            v_ = (v2f){2.f*vv0 - 1.f, 2.f*vv1 - 1.f};
        } else {
            u_ = (v2f){SENT, SENT};
            v_ = (v2f){0.f, 0.f};
        }

        #pragma unroll
        for (int k = 0; k < KC; ++k) {
            const v2f du = u_ + nuc[k];                       // v_pk_add
            const v2f dv = v_ + nvc[k];                       // v_pk_add
            const float tt0 = fmaxf(fabsf(du.x), fabsf(dv.x)); // L1 via Linf
            const float tt1 = fmaxf(fabsf(du.y), fabsf(dv.y));
            const v2f tt = (v2f){tt0, tt1};
            const v2f d1 = tt + one2;                         // v_pk_add
            const float rn0 = r - tt0;
            const float rn1 = r - tt1;
            const v2f d2 = (v2f){1.f + fabsf(rn0), 1.f + fabsf(rn1)};
            const v2f dd  = d1 * d2;                          // v_pk_mul
            const v2f num = d2 - d1;                          // == |rn| - tt
            const v2f rc  = (v2f){__builtin_amdgcn_rcpf(dd.x),
                                  __builtin_amdgcn_rcpf(dd.y)};
            acc[k] = __builtin_elementwise_fma(num, rc, acc[k]); // v_pk_fma
        }
    }

    // fold point-pair halves
    float a1[KC];
    #pragma unroll
    for (int k = 0; k < KC; ++k) a1[k] = acc[k].x + acc[k].y;

    // KC=8 butterfly (R7-validated): center (lane>>3)&7 in a1[0] at (lane&7)==0
    {
        #pragma unroll
        for (int k = 0; k < 4; ++k) {
            const bool hi = lane & 32;
            const float send = hi ? a1[k]   : a1[k+4];
            const float keep = hi ? a1[k+4] : a1[k];
            a1[k] = keep + __shfl_xor(send, 32, 64);
        }
        #pragma unroll
        for (int k = 0; k < 2; ++k) {
            const bool hi = lane & 16;
            const float send = hi ? a1[k]   : a1[k+2];
            const float keep = hi ? a1[k+2] : a1[k];
            a1[k] = keep + __shfl_xor(send, 16, 64);
        }
        {
            const bool hi = lane & 8;
            const float send = hi ? a1[0] : a1[1];
            const float keep = hi ? a1[1] : a1[0];
            a1[0] = keep + __shfl_xor(send, 8, 64);
        }
        a1[0] += __shfl_xor(a1[0], 4, 64);
        a1[0] += __shfl_xor(a1[0], 2, 64);
        a1[0] += __shfl_xor(a1[0], 1, 64);
    }

    __shared__ float red[4 * KC];
    if ((lane & 7) == 0) red[wave * KC + (lane >> 3)] = a1[0];
    __syncthreads();
    if (tid < KC) {
        const float s = red[tid] + red[KC + tid] + red[2*KC + tid] + red[3*KC + tid];
        atomicAdd(&out[b*128 + side*64 + cbase + tid], s);  // 4 contenders
    }
}

__global__ __launch_bounds__(256) void tpl_kernel(float* __restrict__ out)
{
    __shared__ float red[256];
    float s = 0.f;
    for (int i = threadIdx.x; i < NB*64; i += 256) {
        const int b = i >> 6, k = i & 63;
        const float d = out[b*128 + k] - out[b*128 + 64 + k];
        s = fmaf(d, d, s);
    }
    red[threadIdx.x] = s;
    __syncthreads();
    for (int w = 128; w > 0; w >>= 1) {
        if (threadIdx.x < w) red[threadIdx.x] += red[threadIdx.x + w];
        __syncthreads();
    }
    if (threadIdx.x == 0) out[NB*128] = -red[0];
}

extern "C" void kernel_launch(void* const* d_in, const int* in_sizes, int n_in,
                              void* d_out, int out_size, void* d_ws, size_t ws_size,
                              hipStream_t stream) {
    const float* up0     = (const float*)d_in[0];
    const float* down0   = (const float*)d_in[1];
    const float* ext0    = (const float*)d_in[2];
    const float* ext1    = (const float*)d_in[3];
    const float* centers = (const float*)d_in[4];
    const float* radius  = (const float*)d_in[5];
    float* out = (float*)d_out;

    // accumulator region must start at zero (harness poisons d_out with 0xAA)
    hipMemsetAsync(out, 0, NB * 128 * sizeof(float), stream);

    hat_kernel<<<dim3(NB * 2 * 8 * TCHUNKS), dim3(256), 0, stream>>>(
        up0, down0, ext0, ext1, centers, radius, out);
    tpl_kernel<<<1, 256, 0, stream>>>(out);
}

// Round 9
// 107.642 us; speedup vs baseline: 1.1848x; 1.1848x over previous
//
#include <hip/hip_runtime.h>

typedef float v2f __attribute__((ext_vector_type(2)));

#define NB 32
#define N0 20000
#define N1 10000
#define N2 10000
#define NT_A 157           // ceil(10000 float4 / 64)
#define KC_A 8
#define KC_B 16
#define NBINS 4096
#define SENT 3.0e4f        // sentinel: per-term contribution ~ -1e-10

// grid = 256 B-role blocks (binned ext part, 1-D) + 2048 A-role blocks
// (exact beta_0 part). All atomicAdd into memset-zeroed out[0..4095].
__global__ __launch_bounds__(256, 8) void hat_kernel(
    const float* __restrict__ up0, const float* __restrict__ down0,
    const float* __restrict__ ext0, const float* __restrict__ ext1,
    const float* __restrict__ centers, const float* __restrict__ radius,
    float* __restrict__ out)
{
    const int tid  = threadIdx.x;
    const int lane = tid & 63;
    const int wave = tid >> 6;
    const float r  = fabsf(radius[0]);

    __shared__ unsigned hist[NBINS];     // 16 KB (B-role)
    __shared__ float    red[4 * KC_B];   // shared by both roles' reductions

    if (blockIdx.x < 256) {
        // ================= B-role: ext points, 1-D binned =================
        const int id   = blockIdx.x;
        const int cc   = id & 3;         // 4 chunks of 16 centers
        const int side = (id >> 2) & 1;  // 0 = up (use y), 1 = down (use x)
        const int b    = id >> 3;
        const int cbase = cc * KC_B;

        for (int j = tid; j < NBINS; j += 256) hist[j] = 0;
        __syncthreads();

        const float2* e0 = (const float2*)(ext0 + (size_t)b * (N1*2));
        const float2* e1 = (const float2*)(ext1 + (size_t)b * (N2*2));
        for (int i = tid; i < N1; i += 256) {
            const float2 q0 = e0[i];
            const float2 q1 = e1[i];
            const float vv0 = (side == 0) ? q0.y : q0.x;
            const float vv1 = (side == 0) ? q1.y : q1.x;
            int b0 = (int)(vv0 * (float)NBINS);
            int b1 = (int)(vv1 * (float)NBINS);
            b0 = min(max(b0, 0), NBINS - 1);
            b1 = min(max(b1, 0), NBINS - 1);
            atomicAdd(&hist[b0], 1u);
            atomicAdd(&hist[b1], 1u);
        }
        __syncthreads();

        // centers: n_k(vv) = max(|1-uc_k|, 2|vv - (1+vc_k)/2|)
        float Ak[KC_B], mk[KC_B];
        #pragma unroll
        for (int k = 0; k < KC_B; ++k) {
            const float cx = centers[2*(cbase+k)];
            const float cy = centers[2*(cbase+k)+1];
            Ak[k] = fabsf(1.0f - (cx + cy));
            mk[k] = 0.5f * (1.0f + (cx - cy));
        }

        float part[KC_B];
        #pragma unroll
        for (int k = 0; k < KC_B; ++k) part[k] = 0.f;

        #pragma unroll
        for (int jj = 0; jj < NBINS/256; ++jj) {
            const int j = jj*256 + tid;
            const float cntf = (float)hist[j];
            const float vvj  = ((float)j + 0.5f) * (1.0f/(float)NBINS);
            #pragma unroll
            for (int k = 0; k < KC_B; ++k) {
                const float s  = vvj - mk[k];
                const float tt = fmaxf(Ak[k], 2.0f*fabsf(s));
                const float d1 = 1.0f + tt;
                const float rn = r - tt;
                const float d2 = 1.0f + fabsf(rn);
                const float rc = __builtin_amdgcn_rcpf(d1 * d2);
                part[k] = fmaf(cntf * (d2 - d1), rc, part[k]);
            }
        }

        // KC=16 butterfly (R6-validated): center (lane>>2)&15 in part[0]
        {
            #pragma unroll
            for (int k = 0; k < 8; ++k) {
                const bool hi = lane & 32;
                const float send = hi ? part[k]   : part[k+8];
                const float keep = hi ? part[k+8] : part[k];
                part[k] = keep + __shfl_xor(send, 32, 64);
            }
            #pragma unroll
            for (int k = 0; k < 4; ++k) {
                const bool hi = lane & 16;
                const float send = hi ? part[k]   : part[k+4];
                const float keep = hi ? part[k+4] : part[k];
                part[k] = keep + __shfl_xor(send, 16, 64);
            }
            #pragma unroll
            for (int k = 0; k < 2; ++k) {
                const bool hi = lane & 8;
                const float send = hi ? part[k]   : part[k+2];
                const float keep = hi ? part[k+2] : part[k];
                part[k] = keep + __shfl_xor(send, 8, 64);
            }
            {
                const bool hi = lane & 4;
                const float send = hi ? part[0] : part[1];
                const float keep = hi ? part[1] : part[0];
                part[0] = keep + __shfl_xor(send, 4, 64);
            }
            part[0] += __shfl_xor(part[0], 2, 64);
            part[0] += __shfl_xor(part[0], 1, 64);
        }
        if ((lane & 3) == 0) red[wave * KC_B + (lane >> 2)] = part[0];
        __syncthreads();
        if (tid < KC_B) {
            const float s = red[tid] + red[KC_B + tid] + red[2*KC_B + tid] + red[3*KC_B + tid];
            atomicAdd(&out[b*128 + side*64 + cbase + tid], s);
        }
        return;
    }

    // ================= A-role: beta_0 points, exact =================
    const int bid    = blockIdx.x - 256;
    const int tchunk = bid & 3;
    const int cc     = (bid >> 2) & 7;
    const int side   = (bid >> 5) & 1;
    const int b      = bid >> 6;
    const int cbase  = cc * KC_A;

    v2f nuc[KC_A], nvc[KC_A];
    #pragma unroll
    for (int k = 0; k < KC_A; ++k) {
        const float cx = centers[2*(cbase+k)];
        const float cy = centers[2*(cbase+k)+1];
        nuc[k] = (v2f){-(cx + cy), -(cx + cy)};
        nvc[k] = (v2f){-(cx - cy), -(cx - cy)};
    }

    const float4* base0 = (const float4*)((side == 0 ? up0 : down0) + (size_t)b * (N0*2));

    v2f acc[KC_A];
    #pragma unroll
    for (int k = 0; k < KC_A; ++k) acc[k] = (v2f){0.f, 0.f};
    const v2f one2 = (v2f){1.f, 1.f};

    for (int t = tchunk*4 + wave; t < NT_A; t += 16) {
        const int i = t*64 + lane;      // float4 index = two points
        v2f u_, v_;
        if (i < N0/2) {
            const float4 q = base0[i];
            u_ = (v2f){q.x + q.y, q.z + q.w};
            v_ = (v2f){q.x - q.y, q.z - q.w};
        } else {
            u_ = (v2f){SENT, SENT};
            v_ = (v2f){0.f, 0.f};
        }

        #pragma unroll
        for (int k = 0; k < KC_A; ++k) {
            const v2f du = u_ + nuc[k];
            const v2f dv = v_ + nvc[k];
            const float tt0 = fmaxf(fabsf(du.x), fabsf(dv.x));
            const float tt1 = fmaxf(fabsf(du.y), fabsf(dv.y));
            const v2f tt = (v2f){tt0, tt1};
            const v2f d1 = tt + one2;
            const float rn0 = r - tt0;
            const float rn1 = r - tt1;
            const v2f d2 = (v2f){1.f + fabsf(rn0), 1.f + fabsf(rn1)};
            const v2f dd  = d1 * d2;
            const v2f num = d2 - d1;
            const v2f rc  = (v2f){__builtin_amdgcn_rcpf(dd.x),
                                  __builtin_amdgcn_rcpf(dd.y)};
            acc[k] = __builtin_elementwise_fma(num, rc, acc[k]);
        }
    }

    float a1[KC_A];
    #pragma unroll
    for (int k = 0; k < KC_A; ++k) a1[k] = acc[k].x + acc[k].y;

    // KC=8 butterfly (R7/R8-validated): center (lane>>3)&7 at (lane&7)==0
    {
        #pragma unroll
        for (int k = 0; k < 4; ++k) {
            const bool hi = lane & 32;
            const float send = hi ? a1[k]   : a1[k+4];
            const float keep = hi ? a1[k+4] : a1[k];
            a1[k] = keep + __shfl_xor(send, 32, 64);
        }
        #pragma unroll
        for (int k = 0; k < 2; ++k) {
            const bool hi = lane & 16;
            const float send = hi ? a1[k]   : a1[k+2];
            const float keep = hi ? a1[k+2] : a1[k];
            a1[k] = keep + __shfl_xor(send, 16, 64);
        }
        {
            const bool hi = lane & 8;
            const float send = hi ? a1[0] : a1[1];
            const float keep = hi ? a1[1] : a1[0];
            a1[0] = keep + __shfl_xor(send, 8, 64);
        }
        a1[0] += __shfl_xor(a1[0], 4, 64);
        a1[0] += __shfl_xor(a1[0], 2, 64);
        a1[0] += __shfl_xor(a1[0], 1, 64);
    }
    if ((lane & 7) == 0) red[wave * KC_A + (lane >> 3)] = a1[0];
    __syncthreads();
    if (tid < KC_A) {
        const float s = red[tid] + red[KC_A + tid] + red[2*KC_A + tid] + red[3*KC_A + tid];
        atomicAdd(&out[b*128 + side*64 + cbase + tid], s);
    }
}

__global__ __launch_bounds__(256) void tpl_kernel(float* __restrict__ out)
{
    __shared__ float red[256];
    float s = 0.f;
    for (int i = threadIdx.x; i < NB*64; i += 256) {
        const int b = i >> 6, k = i & 63;
        const float d = out[b*128 + k] - out[b*128 + 64 + k];
        s = fmaf(d, d, s);
    }
    red[threadIdx.x] = s;
    __syncthreads();
    for (int w = 128; w > 0; w >>= 1) {
        if (threadIdx.x < w) red[threadIdx.x] += red[threadIdx.x + w];
        __syncthreads();
    }
    if (threadIdx.x == 0) out[NB*128] = -red[0];
}

extern "C" void kernel_launch(void* const* d_in, const int* in_sizes, int n_in,
                              void* d_out, int out_size, void* d_ws, size_t ws_size,
                              hipStream_t stream) {
    const float* up0     = (const float*)d_in[0];
    const float* down0   = (const float*)d_in[1];
    const float* ext0    = (const float*)d_in[2];
    const float* ext1    = (const float*)d_in[3];
    const float* centers = (const float*)d_in[4];
    const float* radius  = (const float*)d_in[5];
    float* out = (float*)d_out;

    // accumulator region must start at zero (harness poisons d_out with 0xAA)
    hipMemsetAsync(out, 0, NB * 128 * sizeof(float), stream);

    hat_kernel<<<dim3(256 + 2048), dim3(256), 0, stream>>>(
        up0, down0, ext0, ext1, centers, radius, out);
    tpl_kernel<<<1, 256, 0, stream>>>(out);
}